// Round 5
// baseline (135.180 us; speedup 1.0000x reference)
//
#include <hip/hip_runtime.h>

#define B_   4
#define NQ_  512
#define NK_  512
#define D_   512
#define H_   128

typedef __attribute__((ext_vector_type(8))) short short8;
typedef __attribute__((ext_vector_type(4))) float f32x4;

__device__ __forceinline__ float fexp2(float x) { return __builtin_amdgcn_exp2f(x); }
__device__ __forceinline__ float frcp(float x)  { return __builtin_amdgcn_rcpf(x); }
__device__ __forceinline__ unsigned short f2bf(float f) {
    unsigned int u = __builtin_bit_cast(unsigned int, f);
    u += 0x7FFFu + ((u >> 16) & 1u);          // RNE
    return (unsigned short)(u >> 16);
}

// ws layout (float offsets)
#define WS_QKP   0          // [4096][128] fp32: Qp rows 0..2047, Kp 2048..4095 (pre-scaled 2*log2e)
#define WS_PP    524288     // [8][4096][128] fp32 proj partials
#define WS_WP    4718592    // [64] float4 pair table (wn0, wn1, wn0+wn1, 0)
#define WS_SC    4718848    // [4][512][512] fp32 raw scores
#define WS_VT    5767424    // ushort region: [4][512][512] bf16 V^T (d-major)

// ---------------------------------------------------------------------------
// prep: blockIdx.x < 32 -> proj partial tiles (identical to R4 proj);
//       blockIdx.x >= 32 -> V transpose tiles (identical to R4 transposeV).
// grid (64, 8), 256 thr.
// ---------------------------------------------------------------------------
__global__ __launch_bounds__(256) void prep_kernel(
    const float* __restrict__ Q, const float* __restrict__ K,
    const float* __restrict__ Wq, const float* __restrict__ Wk,
    const float* __restrict__ V,
    float* __restrict__ Pp, unsigned short* __restrict__ Vt)
{
    __shared__ float smem[2 * 32 * 132];   // 33792 B, aliased per branch
    const int t = threadIdx.x;

    if (blockIdx.x < 32) {
        // ----- proj: partial X@W, k-split 8 -----
        const int xb = blockIdx.x;
        const int ks = blockIdx.y;
        const bool isQ = xb < 16;
        const float* __restrict__ X = isQ ? Q : K;
        const float* __restrict__ W = isQ ? Wq : Wk;
        const int r0 = (xb & 15) * 128;
        const int k0 = ks * 64;

        float (*At)[132] = (float(*)[132])smem;            // [32][132]
        float (*Wl)[132] = (float(*)[132])(smem + 32*132); // [32][132]

        const int cg = t & 15;
        const int rg = t >> 4;
        float acc[8][8] = {};

        for (int kc = 0; kc < 2; ++kc) {
            if (kc) __syncthreads();
            #pragma unroll
            for (int p = 0; p < 4; ++p) {
                const int idx = p * 256 + t;
                const int row = idx & 127;
                const int kq  = (idx >> 7) * 4;
                const float4 v = *reinterpret_cast<const float4*>(
                    X + (size_t)(r0 + row) * D_ + k0 + kc * 32 + kq);
                At[kq + 0][row] = v.x; At[kq + 1][row] = v.y;
                At[kq + 2][row] = v.z; At[kq + 3][row] = v.w;
            }
            #pragma unroll
            for (int p = 0; p < 4; ++p) {
                const int idx = p * 256 + t;
                const int kr  = idx >> 5;
                const int c4  = (idx & 31) * 4;
                *reinterpret_cast<float4*>(&Wl[kr][c4]) =
                    *reinterpret_cast<const float4*>(
                        W + (size_t)(k0 + kc * 32 + kr) * H_ + c4);
            }
            __syncthreads();

            #pragma unroll 4
            for (int k = 0; k < 32; ++k) {
                const float4 a0 = *reinterpret_cast<const float4*>(&At[k][rg * 8]);
                const float4 a1 = *reinterpret_cast<const float4*>(&At[k][rg * 8 + 4]);
                const float4 b0 = *reinterpret_cast<const float4*>(&Wl[k][cg * 4]);
                const float4 b1 = *reinterpret_cast<const float4*>(&Wl[k][64 + cg * 4]);
                const float aa[8] = {a0.x, a0.y, a0.z, a0.w, a1.x, a1.y, a1.z, a1.w};
                const float bb[8] = {b0.x, b0.y, b0.z, b0.w, b1.x, b1.y, b1.z, b1.w};
                #pragma unroll
                for (int r = 0; r < 8; ++r)
                    #pragma unroll
                    for (int c = 0; c < 8; ++c)
                        acc[r][c] = fmaf(aa[r], bb[c], acc[r][c]);
            }
        }

        float* __restrict__ dst = Pp + (size_t)blockIdx.y * (4096 * 128);
        #pragma unroll
        for (int r = 0; r < 8; ++r) {
            const int grow = xb * 128 + rg * 8 + r;
            *reinterpret_cast<float4*>(dst + (size_t)grow * H_ + cg * 4) =
                make_float4(acc[r][0], acc[r][1], acc[r][2], acc[r][3]);
            *reinterpret_cast<float4*>(dst + (size_t)grow * H_ + 64 + cg * 4) =
                make_float4(acc[r][4], acc[r][5], acc[r][6], acc[r][7]);
        }
    } else {
        // ----- transposeV: V (k-major fp32) -> Vt (d-major bf16) -----
        const int id = (blockIdx.x - 32) * 8 + blockIdx.y;   // 0..255
        const int kt = id & 7, dt = (id >> 3) & 7, b = id >> 6;
        float (*Vl)[69] = (float(*)[69])smem;                // [64][69]

        #pragma unroll
        for (int p = 0; p < 4; ++p) {
            const int idx = p * 256 + t;
            const int r  = idx >> 4;
            const int c4 = (idx & 15) * 4;
            const float4 v = *reinterpret_cast<const float4*>(
                V + ((size_t)b * NK_ + kt * 64 + r) * D_ + dt * 64 + c4);
            Vl[r][c4 + 0] = v.x; Vl[r][c4 + 1] = v.y;
            Vl[r][c4 + 2] = v.z; Vl[r][c4 + 3] = v.w;
        }
        __syncthreads();

        #pragma unroll
        for (int p = 0; p < 4; ++p) {
            const int idx = p * 256 + t;
            const int d  = idx >> 4;
            const int k4 = (idx & 15) * 4;
            ushort4 o;
            o.x = f2bf(Vl[k4 + 0][d]); o.y = f2bf(Vl[k4 + 1][d]);
            o.z = f2bf(Vl[k4 + 2][d]); o.w = f2bf(Vl[k4 + 3][d]);
            *reinterpret_cast<ushort4*>(
                Vt + ((size_t)b * D_ + dt * 64 + d) * NK_ + kt * 64 + k4) = o;
        }
    }
}

// ---------------------------------------------------------------------------
// proj_add: QKp = C2 * sum_s Pp[s]; builds wp pair table. grid 512, 256 thr.
// ---------------------------------------------------------------------------
__global__ __launch_bounds__(256) void proj_add_kernel(
    const float* __restrict__ Pp, const float* __restrict__ wv,
    float* __restrict__ QKp, float* __restrict__ wp)
{
    const int i = blockIdx.x * 256 + threadIdx.x;   // f4 index < 131072
    const float C2 = 2.88539008177792681472f;       // 2*log2(e)
    float4 s = make_float4(0.f, 0.f, 0.f, 0.f);
    #pragma unroll
    for (int p = 0; p < 8; ++p) {
        const float4 v = reinterpret_cast<const float4*>(Pp)[(size_t)p * 131072 + i];
        s.x += v.x; s.y += v.y; s.z += v.z; s.w += v.w;
    }
    s.x *= C2; s.y *= C2; s.z *= C2; s.w *= C2;
    reinterpret_cast<float4*>(QKp)[i] = s;

    if (blockIdx.x == 0 && threadIdx.x < 64) {
        const float2 w2 = reinterpret_cast<const float2*>(wv)[threadIdx.x];
        const float wn0 = -2.0f * w2.x;
        const float wn1 = -2.0f * w2.y;
        reinterpret_cast<float4*>(wp)[threadIdx.x] =
            make_float4(wn0, wn1, wn0 + wn1, 0.0f);
    }
}

// ---------------------------------------------------------------------------
// score: raw scores, k-split 4 for occupancy. grid (256, 4), 512 thr
// (8 waves = 8 q-rows; wave w -> row blockIdx.x*8 + w; lane = k within
// 64-chunk; 2 chunks per block). 4-way reciprocal fusion (exact):
//   sum_{i=0..3} wn_i/(1+e_i) = [n01*D23 + n23*D01] / (D01*D23)
//   D01=(1+e0)(1+e1)=1+e0+e1+e0e1, n01=s01+wn0*e1+wn1*e0
// -> 4 exp2 + 1 rcp per 4 h.
// ---------------------------------------------------------------------------
__global__ __launch_bounds__(512, 8) void score_kernel(
    const float* __restrict__ QKp, const float* __restrict__ wp,
    float* __restrict__ Sc)
{
    const int b    = blockIdx.x >> 6;
    const int ks   = blockIdx.y;              // 0..3
    const int t    = threadIdx.x;
    const int w    = __builtin_amdgcn_readfirstlane(t >> 6);   // 0..7
    const int lane = t & 63;
    const int row  = blockIdx.x * 8 + w;      // global q-row (b*512+q)

    __shared__ __align__(16) float4 Ks[64][33];

    const float4* __restrict__ Q4 =
        reinterpret_cast<const float4*>(QKp + (size_t)row * H_);
    const float4* __restrict__ wp4 = reinterpret_cast<const float4*>(wp);
    const float4* __restrict__ Kp4 =
        reinterpret_cast<const float4*>(QKp + (size_t)(2048 + b * NK_) * H_);

    for (int c = 0; c < 2; ++c) {
        if (c) __syncthreads();
        #pragma unroll
        for (int p = 0; p < 4; ++p) {
            const int idx = p * 512 + t;       // 0..2047
            const int r   = idx >> 5;          // 0..63
            const int h4  = idx & 31;
            Ks[r][h4] = Kp4[(size_t)(ks * 128 + c * 64 + r) * 32 + h4];
        }
        __syncthreads();

        float s = 0.0f;
        #pragma unroll 4
        for (int g = 0; g < 32; ++g) {
            const float4 kv = Ks[lane][g];
            const float4 qa = Q4[g];
            const float4 wa = wp4[2 * g];
            const float4 wb = wp4[2 * g + 1];
            const float e0 = fexp2(qa.x + kv.x);
            const float e1 = fexp2(qa.y + kv.y);
            const float e2 = fexp2(qa.z + kv.z);
            const float e3 = fexp2(qa.w + kv.w);
            const float p01 = fmaf(e0, e1, e0 + e1);
            const float p23 = fmaf(e2, e3, e2 + e3);
            const float D01 = 1.0f + p01;
            const float D23 = 1.0f + p23;
            const float n01 = fmaf(wa.y, e0, fmaf(wa.x, e1, wa.z));
            const float n23 = fmaf(wb.y, e2, fmaf(wb.x, e3, wb.z));
            const float N   = fmaf(n23, D01, n01 * D23);
            s = fmaf(N, frcp(D01 * D23), s);
        }
        Sc[(size_t)row * NK_ + ks * 128 + c * 64 + lane] = s;
    }
}

// ---------------------------------------------------------------------------
// gemm_softmax: per-block row softmax stats + bf16 weight materialization in
// LDS + MFMA A@V. Block = 64q x 64d, 512 thr (8 waves), grid (8,8,4).
// Wave w: MFMA rows (w&3)*16, cols (w>>2)*32.
// ---------------------------------------------------------------------------
__global__ __launch_bounds__(512) void gemm_softmax_kernel(
    const float* __restrict__ Sc, const unsigned short* __restrict__ Vt,
    const int* __restrict__ valid_lens, float* __restrict__ O)
{
    const int c0 = blockIdx.x * 64;
    const int r0 = blockIdx.y * 64;
    const int b  = blockIdx.z;
    const int t  = threadIdx.x;
    const int wave = __builtin_amdgcn_readfirstlane(t >> 6);
    const int lane = t & 63;
    const int m    = lane & 15;
    const int quad = lane >> 4;
    const int vl   = valid_lens[b];
    const float L2E = 1.44269504088896340736f;

    __shared__ unsigned short Al [64][136];   // bf16 softmax weights [q][k-chunk]
    __shared__ unsigned short Btl[64][136];   // bf16 V^T tile [d][k-chunk]
    __shared__ float rowM[64], rowI[64];

    // ---- phase 1: per-row max & inv-sum (wave w handles rows w*8..w*8+7) ----
    #pragma unroll
    for (int rr = 0; rr < 8; ++rr) {
        const int rl = wave * 8 + rr;
        const float4* __restrict__ srow =
            reinterpret_cast<const float4*>(Sc + ((size_t)b * NQ_ + r0 + rl) * NK_);
        const float4 v0 = srow[lane * 2];
        const float4 v1 = srow[lane * 2 + 1];
        float v[8] = {v0.x, v0.y, v0.z, v0.w, v1.x, v1.y, v1.z, v1.w};
        float mx = -1e30f;
        #pragma unroll
        for (int j = 0; j < 8; ++j) {
            v[j] = (lane * 8 + j < vl) ? v[j] : -1e30f;
            mx = fmaxf(mx, v[j]);
        }
        #pragma unroll
        for (int off = 32; off >= 1; off >>= 1)
            mx = fmaxf(mx, __shfl_xor(mx, off, 64));
        float sum = 0.0f;
        #pragma unroll
        for (int j = 0; j < 8; ++j)
            sum += fexp2((v[j] - mx) * L2E);
        #pragma unroll
        for (int off = 32; off >= 1; off >>= 1)
            sum += __shfl_xor(sum, off, 64);
        if (lane == 0) { rowM[rl] = mx; rowI[rl] = frcp(sum); }
    }

    f32x4 acc0 = {0.f,0.f,0.f,0.f}, acc1 = {0.f,0.f,0.f,0.f};

    // ---- phase 2: k-chunks of 128 ----
    for (int kc = 0; kc < 4; ++kc) {
        __syncthreads();   // rowM/rowI ready (kc=0); Al/Btl consumed (kc>0)
        // stage V^T tile
        #pragma unroll
        for (int p = 0; p < 2; ++p) {
            const int idx = p * 512 + t;          // 0..1023
            const int rl = idx >> 4;              // 0..63
            const int k8 = (idx & 15) * 8;
            *reinterpret_cast<uint4*>(&Btl[rl][k8]) =
                *reinterpret_cast<const uint4*>(
                    Vt + ((size_t)b * D_ + c0 + rl) * NK_ + kc * 128 + k8);
        }
        // materialize bf16 weights for this chunk
        #pragma unroll
        for (int p = 0; p < 4; ++p) {
            const int idx = p * 512 + t;          // 0..2047
            const int rl = idx >> 5;              // 0..63
            const int kg = idx & 31;              // f4 group within chunk
            const float4 s4 = reinterpret_cast<const float4*>(
                Sc + ((size_t)b * NQ_ + r0 + rl) * NK_)[kc * 32 + kg];
            const float mr = rowM[rl];
            const float ir = rowI[rl];
            const int kk = kc * 128 + kg * 4;
            ushort4 o;
            o.x = (kk + 0 < vl) ? f2bf(fexp2((s4.x - mr) * L2E) * ir) : (unsigned short)0;
            o.y = (kk + 1 < vl) ? f2bf(fexp2((s4.y - mr) * L2E) * ir) : (unsigned short)0;
            o.z = (kk + 2 < vl) ? f2bf(fexp2((s4.z - mr) * L2E) * ir) : (unsigned short)0;
            o.w = (kk + 3 < vl) ? f2bf(fexp2((s4.w - mr) * L2E) * ir) : (unsigned short)0;
            *reinterpret_cast<ushort4*>(&Al[rl][kg * 4]) = o;
        }
        __syncthreads();

        #pragma unroll
        for (int s = 0; s < 4; ++s) {
            const int kcol = s * 32 + quad * 8;
            const short8 a  = *reinterpret_cast<const short8*>(
                &Al[(wave & 3) * 16 + m][kcol]);
            const short8 b0 = *reinterpret_cast<const short8*>(
                &Btl[(wave >> 2) * 32 + m][kcol]);
            const short8 b1 = *reinterpret_cast<const short8*>(
                &Btl[(wave >> 2) * 32 + 16 + m][kcol]);
            acc0 = __builtin_amdgcn_mfma_f32_16x16x32_bf16(a, b0, acc0, 0, 0, 0);
            acc1 = __builtin_amdgcn_mfma_f32_16x16x32_bf16(a, b1, acc1, 0, 0, 0);
        }
    }

    const size_t rowbase = (size_t)b * NQ_ + r0 + (wave & 3) * 16 + quad * 4;
    const int colbase = c0 + (wave >> 2) * 32 + m;
    #pragma unroll
    for (int i = 0; i < 4; ++i) {
        float* __restrict__ orow = O + (rowbase + i) * D_ + colbase;
        orow[ 0] = acc0[i];
        orow[16] = acc1[i];
    }
}

extern "C" void kernel_launch(void* const* d_in, const int* in_sizes, int n_in,
                              void* d_out, int out_size, void* d_ws, size_t ws_size,
                              hipStream_t stream) {
    (void)in_sizes; (void)n_in; (void)out_size; (void)ws_size;

    const float* Q   = (const float*)d_in[0];
    const float* K   = (const float*)d_in[1];
    const float* V   = (const float*)d_in[2];
    const float* Wq  = (const float*)d_in[3];
    const float* Wk  = (const float*)d_in[4];
    const float* wv  = (const float*)d_in[5];
    const int*   vl  = (const int*)d_in[6];
    float* out = (float*)d_out;

    float* ws  = (float*)d_ws;
    float* QKp = ws + WS_QKP;
    float* Pp  = ws + WS_PP;
    float* wp  = ws + WS_WP;
    float* Sc  = ws + WS_SC;
    unsigned short* Vt = (unsigned short*)(ws + WS_VT);

    prep_kernel<<<dim3(64, 8), 256, 0, stream>>>(Q, K, Wq, Wk, V, Pp, Vt);
    proj_add_kernel<<<dim3(512), 256, 0, stream>>>(Pp, wv, QKp, wp);
    score_kernel<<<dim3(256, 4), 512, 0, stream>>>(QKp, wp, Sc);
    gemm_softmax_kernel<<<dim3(8, 8, 4), 512, 0, stream>>>(Sc, Vt, vl, out);
}

// Round 7
// 125.670 us; speedup vs baseline: 1.0757x; 1.0757x over previous
//
#include <hip/hip_runtime.h>

#define B_   4
#define NQ_  512
#define NK_  512
#define D_   512
#define H_   128

typedef __attribute__((ext_vector_type(8))) short short8;
typedef __attribute__((ext_vector_type(4))) float f32x4;

__device__ __forceinline__ float fexp2(float x) { return __builtin_amdgcn_exp2f(x); }
__device__ __forceinline__ float frcp(float x)  { return __builtin_amdgcn_rcpf(x); }
__device__ __forceinline__ unsigned short f2bf(float f) {
    unsigned int u = __builtin_bit_cast(unsigned int, f);
    u += 0x7FFFu + ((u >> 16) & 1u);          // RNE
    return (unsigned short)(u >> 16);
}

// NOTE (R6 lesson): hipLaunchCooperativeKernel silently fails under this
// harness's graph capture — kernel never runs. Ordinary launches only.

// ws layout (float offsets)
#define WS_QKP   0          // [4096][128] fp32 (Qp 0..2047, Kp 2048..4095), pre-scaled 2*log2e
#define WS_PP    524288     // [8][4096][128] fp32 proj partials
#define WS_WP    4718592    // [64] float4 pair table (wn0, wn1, wn0+wn1, 0)
#define WS_SC    4718848    // [2048][512] fp32 raw scores
#define WS_VT    5767424    // ushort region: [4][512][512] bf16 V^T (d-major)
#define WS_WBF   6291712    // ushort region: [4][512][512] bf16 softmax weights

// ---------------------------------------------------------------------------
// prep: blockIdx.x < 32 -> proj partials (128x128 tile, k-split 8);
//       blockIdx.x >= 32 -> V transpose -> bf16 V^T. grid (64,8), 256 thr.
// ---------------------------------------------------------------------------
__global__ __launch_bounds__(256) void prep_kernel(
    const float* __restrict__ Q, const float* __restrict__ K,
    const float* __restrict__ Wq, const float* __restrict__ Wk,
    const float* __restrict__ V,
    float* __restrict__ Pp, unsigned short* __restrict__ Vt)
{
    __shared__ float smem[2 * 32 * 132];
    const int t = threadIdx.x;

    if (blockIdx.x < 32) {
        const int xb = blockIdx.x;
        const int ks = blockIdx.y;
        const bool isQ = xb < 16;
        const float* __restrict__ X = isQ ? Q : K;
        const float* __restrict__ W = isQ ? Wq : Wk;
        const int r0 = (xb & 15) * 128;
        const int k0 = ks * 64;

        float (*At)[132] = (float(*)[132])smem;
        float (*Wl)[132] = (float(*)[132])(smem + 32 * 132);

        const int cg = t & 15;
        const int rg = t >> 4;
        float acc[8][8] = {};

        for (int kc = 0; kc < 2; ++kc) {
            if (kc) __syncthreads();
            #pragma unroll
            for (int p = 0; p < 4; ++p) {
                const int idx = p * 256 + t;
                const int row = idx & 127;
                const int kq  = (idx >> 7) * 4;
                const float4 v = *reinterpret_cast<const float4*>(
                    X + (size_t)(r0 + row) * D_ + k0 + kc * 32 + kq);
                At[kq + 0][row] = v.x; At[kq + 1][row] = v.y;
                At[kq + 2][row] = v.z; At[kq + 3][row] = v.w;
            }
            #pragma unroll
            for (int p = 0; p < 4; ++p) {
                const int idx = p * 256 + t;
                const int kr  = idx >> 5;
                const int c4  = (idx & 31) * 4;
                *reinterpret_cast<float4*>(&Wl[kr][c4]) =
                    *reinterpret_cast<const float4*>(
                        W + (size_t)(k0 + kc * 32 + kr) * H_ + c4);
            }
            __syncthreads();

            #pragma unroll 4
            for (int k = 0; k < 32; ++k) {
                const float4 a0 = *reinterpret_cast<const float4*>(&At[k][rg * 8]);
                const float4 a1 = *reinterpret_cast<const float4*>(&At[k][rg * 8 + 4]);
                const float4 b0 = *reinterpret_cast<const float4*>(&Wl[k][cg * 4]);
                const float4 b1 = *reinterpret_cast<const float4*>(&Wl[k][64 + cg * 4]);
                const float aa[8] = {a0.x, a0.y, a0.z, a0.w, a1.x, a1.y, a1.z, a1.w};
                const float bb[8] = {b0.x, b0.y, b0.z, b0.w, b1.x, b1.y, b1.z, b1.w};
                #pragma unroll
                for (int r = 0; r < 8; ++r)
                    #pragma unroll
                    for (int c = 0; c < 8; ++c)
                        acc[r][c] = fmaf(aa[r], bb[c], acc[r][c]);
            }
        }

        float* __restrict__ dst = Pp + (size_t)blockIdx.y * (4096 * 128);
        #pragma unroll
        for (int r = 0; r < 8; ++r) {
            const int grow = xb * 128 + rg * 8 + r;
            *reinterpret_cast<float4*>(dst + (size_t)grow * H_ + cg * 4) =
                make_float4(acc[r][0], acc[r][1], acc[r][2], acc[r][3]);
            *reinterpret_cast<float4*>(dst + (size_t)grow * H_ + 64 + cg * 4) =
                make_float4(acc[r][4], acc[r][5], acc[r][6], acc[r][7]);
        }
    } else {
        const int id = (blockIdx.x - 32) * 8 + blockIdx.y;
        const int kt = id & 7, dt = (id >> 3) & 7, b = id >> 6;
        float (*Vl)[69] = (float(*)[69])smem;

        #pragma unroll
        for (int p = 0; p < 4; ++p) {
            const int idx = p * 256 + t;
            const int r  = idx >> 4;
            const int c4 = (idx & 15) * 4;
            const float4 v = *reinterpret_cast<const float4*>(
                V + ((size_t)b * NK_ + kt * 64 + r) * D_ + dt * 64 + c4);
            Vl[r][c4 + 0] = v.x; Vl[r][c4 + 1] = v.y;
            Vl[r][c4 + 2] = v.z; Vl[r][c4 + 3] = v.w;
        }
        __syncthreads();

        #pragma unroll
        for (int p = 0; p < 4; ++p) {
            const int idx = p * 256 + t;
            const int d  = idx >> 4;
            const int k4 = (idx & 15) * 4;
            ushort4 o;
            o.x = f2bf(Vl[k4 + 0][d]); o.y = f2bf(Vl[k4 + 1][d]);
            o.z = f2bf(Vl[k4 + 2][d]); o.w = f2bf(Vl[k4 + 3][d]);
            *reinterpret_cast<ushort4*>(
                Vt + ((size_t)b * D_ + dt * 64 + d) * NK_ + kt * 64 + k4) = o;
        }
    }
}

// ---------------------------------------------------------------------------
// proj_add: QKp = C2 * sum_s Pp[s]; builds wp pair table. grid 512, 256 thr.
// ---------------------------------------------------------------------------
__global__ __launch_bounds__(256) void proj_add_kernel(
    const float* __restrict__ Pp, const float* __restrict__ wv,
    float* __restrict__ QKp, float* __restrict__ wp)
{
    const int i = blockIdx.x * 256 + threadIdx.x;
    const float C2 = 2.88539008177792681472f;       // 2*log2(e)
    float4 s = make_float4(0.f, 0.f, 0.f, 0.f);
    #pragma unroll
    for (int p = 0; p < 8; ++p) {
        const float4 v = reinterpret_cast<const float4*>(Pp)[(size_t)p * 131072 + i];
        s.x += v.x; s.y += v.y; s.z += v.z; s.w += v.w;
    }
    s.x *= C2; s.y *= C2; s.z *= C2; s.w *= C2;
    reinterpret_cast<float4*>(QKp)[i] = s;

    if (blockIdx.x == 0 && threadIdx.x < 64) {
        const float2 w2 = reinterpret_cast<const float2*>(wv)[threadIdx.x];
        const float wn0 = -2.0f * w2.x;
        const float wn1 = -2.0f * w2.y;
        reinterpret_cast<float4*>(wp)[threadIdx.x] =
            make_float4(wn0, wn1, wn0 + wn1, 0.0f);
    }
}

// ---------------------------------------------------------------------------
// score: raw scores. grid (128, 4), 512 thr. Block = 16 q-rows (wave w ->
// rows rb*16 + 2w, +1) x 128 k (ks*128, two 64-chunks). 2 rows/wave share
// each Ks read. 4-way rcp fusion: 4 exp2 + 1 rcp per 4 h per row.
// __launch_bounds__(512,4): 128-VGPR cap (no spill; R5's (512,8)=64-cap
// is the suspected spill regression).
// ---------------------------------------------------------------------------
__global__ __launch_bounds__(512, 4) void score_kernel(
    const float* __restrict__ QKp, const float* __restrict__ wp,
    float* __restrict__ Sc)
{
    const int rb   = blockIdx.x;              // 0..127
    const int ks   = blockIdx.y;              // 0..3
    const int b    = rb >> 5;
    const int t    = threadIdx.x;
    const int w    = __builtin_amdgcn_readfirstlane(t >> 6);   // 0..7
    const int lane = t & 63;
    const int row0 = rb * 16 + w * 2;         // global q-row

    __shared__ __align__(16) float4 Ks[64][33];

    const float4* __restrict__ Q4a =
        reinterpret_cast<const float4*>(QKp + (size_t)row0 * H_);
    const float4* __restrict__ Q4b = Q4a + 32;
    const float4* __restrict__ wp4 = reinterpret_cast<const float4*>(wp);
    const float4* __restrict__ Kp4 =
        reinterpret_cast<const float4*>(QKp + (size_t)(2048 + b * NK_) * H_);

    for (int c = 0; c < 2; ++c) {
        if (c) __syncthreads();
        #pragma unroll
        for (int p = 0; p < 4; ++p) {
            const int idx = p * 512 + t;       // 0..2047
            const int r   = idx >> 5;          // 0..63
            const int h4  = idx & 31;
            Ks[r][h4] = Kp4[(size_t)(ks * 128 + c * 64 + r) * 32 + h4];
        }
        __syncthreads();

        float sA = 0.0f, sB = 0.0f;
        #pragma unroll 4
        for (int g = 0; g < 32; ++g) {
            const float4 kv = Ks[lane][g];
            const float4 qa = Q4a[g];
            const float4 qb = Q4b[g];
            const float4 wa = wp4[2 * g];
            const float4 wb = wp4[2 * g + 1];
            {
                const float e0 = fexp2(qa.x + kv.x);
                const float e1 = fexp2(qa.y + kv.y);
                const float e2 = fexp2(qa.z + kv.z);
                const float e3 = fexp2(qa.w + kv.w);
                const float D01 = 1.0f + fmaf(e0, e1, e0 + e1);
                const float D23 = 1.0f + fmaf(e2, e3, e2 + e3);
                const float n01 = fmaf(wa.y, e0, fmaf(wa.x, e1, wa.z));
                const float n23 = fmaf(wb.y, e2, fmaf(wb.x, e3, wb.z));
                const float N   = fmaf(n23, D01, n01 * D23);
                sA = fmaf(N, frcp(D01 * D23), sA);
            }
            {
                const float e0 = fexp2(qb.x + kv.x);
                const float e1 = fexp2(qb.y + kv.y);
                const float e2 = fexp2(qb.z + kv.z);
                const float e3 = fexp2(qb.w + kv.w);
                const float D01 = 1.0f + fmaf(e0, e1, e0 + e1);
                const float D23 = 1.0f + fmaf(e2, e3, e2 + e3);
                const float n01 = fmaf(wa.y, e0, fmaf(wa.x, e1, wa.z));
                const float n23 = fmaf(wb.y, e2, fmaf(wb.x, e3, wb.z));
                const float N   = fmaf(n23, D01, n01 * D23);
                sB = fmaf(N, frcp(D01 * D23), sB);
            }
        }
        const size_t so = (size_t)row0 * NK_ + ks * 128 + c * 64 + lane;
        Sc[so]       = sA;
        Sc[so + NK_] = sB;
    }
}

// ---------------------------------------------------------------------------
// softmax: wave per row, masked, writes bf16 weights (contiguous ushort4).
// grid 512, 256 thr.
// ---------------------------------------------------------------------------
__global__ __launch_bounds__(256) void softmax_kernel(
    const float* __restrict__ Sc, const int* __restrict__ valid_lens,
    unsigned short* __restrict__ Wbf)
{
    const int row  = blockIdx.x * 4 + (threadIdx.x >> 6);   // 0..2047
    const int lane = threadIdx.x & 63;
    const int b    = row >> 9;
    const int vl   = valid_lens[b];
    const float L2E = 1.44269504088896340736f;

    const float4* __restrict__ srow =
        reinterpret_cast<const float4*>(Sc + (size_t)row * NK_);
    const float4 v0 = srow[lane * 2];
    const float4 v1 = srow[lane * 2 + 1];
    float v[8] = {v0.x, v0.y, v0.z, v0.w, v1.x, v1.y, v1.z, v1.w};

    const int k0 = lane * 8;
    float m = -1e30f;
    #pragma unroll
    for (int j = 0; j < 8; ++j) {
        v[j] = (k0 + j < vl) ? v[j] : -1e30f;
        m = fmaxf(m, v[j]);
    }
    #pragma unroll
    for (int off = 32; off >= 1; off >>= 1)
        m = fmaxf(m, __shfl_xor(m, off, 64));

    float e[8];
    float sum = 0.0f;
    #pragma unroll
    for (int j = 0; j < 8; ++j) {
        e[j] = fexp2((v[j] - m) * L2E);
        sum += e[j];
    }
    #pragma unroll
    for (int off = 32; off >= 1; off >>= 1)
        sum += __shfl_xor(sum, off, 64);

    const float inv = frcp(sum);
    unsigned short* __restrict__ dst = Wbf + (size_t)row * NK_ + k0;
    ushort4 o0, o1;
    o0.x = f2bf(e[0] * inv); o0.y = f2bf(e[1] * inv);
    o0.z = f2bf(e[2] * inv); o0.w = f2bf(e[3] * inv);
    o1.x = f2bf(e[4] * inv); o1.y = f2bf(e[5] * inv);
    o1.z = f2bf(e[6] * inv); o1.w = f2bf(e[7] * inv);
    *reinterpret_cast<ushort4*>(dst)     = o0;
    *reinterpret_cast<ushort4*>(dst + 4) = o1;
}

// ---------------------------------------------------------------------------
// av_gemm (bf16 MFMA 16x16x32): O[b] = W@V. Block 64q x 64d, 4 waves,
// grid (8,8,4). A (weights) and Bt (=V^T) k-contiguous -> ds_read_b128.
// ---------------------------------------------------------------------------
__global__ __launch_bounds__(256) void av_gemm_kernel(
    const unsigned short* __restrict__ Wbf, const unsigned short* __restrict__ Vt,
    float* __restrict__ O)
{
    const int c0 = blockIdx.x * 64;
    const int r0 = blockIdx.y * 64;
    const int b  = blockIdx.z;
    const int t  = threadIdx.x;
    const int wave = __builtin_amdgcn_readfirstlane(t >> 6);
    const int lane = t & 63;
    const int m    = lane & 15;
    const int quad = lane >> 4;

    __shared__ unsigned short Al [64][136];
    __shared__ unsigned short Btl[64][136];

    f32x4 acc0 = {0.f,0.f,0.f,0.f}, acc1 = {0.f,0.f,0.f,0.f};
    f32x4 acc2 = {0.f,0.f,0.f,0.f}, acc3 = {0.f,0.f,0.f,0.f};

    for (int kc = 0; kc < 4; ++kc) {
        if (kc) __syncthreads();
        #pragma unroll
        for (int p = 0; p < 4; ++p) {
            const int idx = p * 256 + t;
            const int rl = idx >> 4;
            const int k8 = (idx & 15) * 8;
            *reinterpret_cast<uint4*>(&Al[rl][k8]) =
                *reinterpret_cast<const uint4*>(
                    Wbf + ((size_t)b * NQ_ + r0 + rl) * NK_ + kc * 128 + k8);
            *reinterpret_cast<uint4*>(&Btl[rl][k8]) =
                *reinterpret_cast<const uint4*>(
                    Vt + ((size_t)b * D_ + c0 + rl) * NK_ + kc * 128 + k8);
        }
        __syncthreads();

        #pragma unroll
        for (int sub = 0; sub < 4; ++sub) {
            const int kcol = sub * 32 + quad * 8;
            const short8 a = *reinterpret_cast<const short8*>(&Al[wave * 16 + m][kcol]);
            const short8 b0 = *reinterpret_cast<const short8*>(&Btl[ 0 + m][kcol]);
            const short8 b1 = *reinterpret_cast<const short8*>(&Btl[16 + m][kcol]);
            const short8 b2 = *reinterpret_cast<const short8*>(&Btl[32 + m][kcol]);
            const short8 b3 = *reinterpret_cast<const short8*>(&Btl[48 + m][kcol]);
            acc0 = __builtin_amdgcn_mfma_f32_16x16x32_bf16(a, b0, acc0, 0, 0, 0);
            acc1 = __builtin_amdgcn_mfma_f32_16x16x32_bf16(a, b1, acc1, 0, 0, 0);
            acc2 = __builtin_amdgcn_mfma_f32_16x16x32_bf16(a, b2, acc2, 0, 0, 0);
            acc3 = __builtin_amdgcn_mfma_f32_16x16x32_bf16(a, b3, acc3, 0, 0, 0);
        }
    }

    const size_t rowbase = (size_t)b * NQ_ + r0 + wave * 16 + quad * 4;
    #pragma unroll
    for (int i = 0; i < 4; ++i) {
        float* __restrict__ orow = O + (rowbase + i) * D_ + c0 + m;
        orow[ 0] = acc0[i];
        orow[16] = acc1[i];
        orow[32] = acc2[i];
        orow[48] = acc3[i];
    }
}

extern "C" void kernel_launch(void* const* d_in, const int* in_sizes, int n_in,
                              void* d_out, int out_size, void* d_ws, size_t ws_size,
                              hipStream_t stream) {
    (void)in_sizes; (void)n_in; (void)out_size; (void)ws_size;

    const float* Q   = (const float*)d_in[0];
    const float* K   = (const float*)d_in[1];
    const float* V   = (const float*)d_in[2];
    const float* Wq  = (const float*)d_in[3];
    const float* Wk  = (const float*)d_in[4];
    const float* wv  = (const float*)d_in[5];
    const int*   vl  = (const int*)d_in[6];
    float* out = (float*)d_out;

    float* ws  = (float*)d_ws;
    float* QKp = ws + WS_QKP;
    float* Pp  = ws + WS_PP;
    float* wp  = ws + WS_WP;
    float* Sc  = ws + WS_SC;
    unsigned short* Vt  = (unsigned short*)(ws + WS_VT);
    unsigned short* Wbf = (unsigned short*)(ws + WS_WBF);

    prep_kernel<<<dim3(64, 8), 256, 0, stream>>>(Q, K, Wq, Wk, V, Pp, Vt);
    proj_add_kernel<<<dim3(512), 256, 0, stream>>>(Pp, wv, QKp, wp);
    score_kernel<<<dim3(128, 4), 512, 0, stream>>>(QKp, wp, Sc);
    softmax_kernel<<<dim3(512), 256, 0, stream>>>(Sc, vl, Wbf);
    av_gemm_kernel<<<dim3(8, 8, 4), 256, 0, stream>>>(Wbf, Vt, out);
}

// Round 8
// 121.382 us; speedup vs baseline: 1.1137x; 1.0353x over previous
//
#include <hip/hip_runtime.h>

#define B_   4
#define NQ_  512
#define NK_  512
#define D_   512
#define H_   128

typedef __attribute__((ext_vector_type(8))) short short8;
typedef __attribute__((ext_vector_type(4))) float f32x4;

__device__ __forceinline__ float fexp2(float x) { return __builtin_amdgcn_exp2f(x); }
__device__ __forceinline__ float frcp(float x)  { return __builtin_amdgcn_rcpf(x); }
__device__ __forceinline__ unsigned short f2bf(float f) {
    unsigned int u = __builtin_bit_cast(unsigned int, f);
    u += 0x7FFFu + ((u >> 16) & 1u);          // RNE
    return (unsigned short)(u >> 16);
}

// NOTE (R6 lesson): hipLaunchCooperativeKernel silently fails under this
// harness's graph capture — ordinary stream launches only.

// ws layout (float offsets)
#define WS_EQK   0          // [4096][128] fp32: exp2(C2*proj) for Q rows 0..2047, K rows 2048..4095
#define WS_PP    524288     // [8][4096][128] fp32 proj partials
#define WS_WP    4718592    // [64] float4 pair table (wn0, wn1, wn0+wn1, 0)
#define WS_WBF   4718848    // ushort region: [4][512][512] bf16 softmax weights
#define WS_VT    5243136    // ushort region: [4][512][512] bf16 V^T (d-major)

// ---------------------------------------------------------------------------
// prep: blockIdx.x < 32 -> proj partials (128x128 tile, k-split 8);
//       blockIdx.x >= 32 -> V transpose -> bf16 V^T. grid (64,8), 256 thr.
// ---------------------------------------------------------------------------
__global__ __launch_bounds__(256) void prep_kernel(
    const float* __restrict__ Q, const float* __restrict__ K,
    const float* __restrict__ Wq, const float* __restrict__ Wk,
    const float* __restrict__ V,
    float* __restrict__ Pp, unsigned short* __restrict__ Vt)
{
    __shared__ float smem[2 * 32 * 132];
    const int t = threadIdx.x;

    if (blockIdx.x < 32) {
        const int xb = blockIdx.x;
        const int ks = blockIdx.y;
        const bool isQ = xb < 16;
        const float* __restrict__ X = isQ ? Q : K;
        const float* __restrict__ W = isQ ? Wq : Wk;
        const int r0 = (xb & 15) * 128;
        const int k0 = ks * 64;

        float (*At)[132] = (float(*)[132])smem;
        float (*Wl)[132] = (float(*)[132])(smem + 32 * 132);

        const int cg = t & 15;
        const int rg = t >> 4;
        float acc[8][8] = {};

        for (int kc = 0; kc < 2; ++kc) {
            if (kc) __syncthreads();
            #pragma unroll
            for (int p = 0; p < 4; ++p) {
                const int idx = p * 256 + t;
                const int row = idx & 127;
                const int kq  = (idx >> 7) * 4;
                const float4 v = *reinterpret_cast<const float4*>(
                    X + (size_t)(r0 + row) * D_ + k0 + kc * 32 + kq);
                At[kq + 0][row] = v.x; At[kq + 1][row] = v.y;
                At[kq + 2][row] = v.z; At[kq + 3][row] = v.w;
            }
            #pragma unroll
            for (int p = 0; p < 4; ++p) {
                const int idx = p * 256 + t;
                const int kr  = idx >> 5;
                const int c4  = (idx & 31) * 4;
                *reinterpret_cast<float4*>(&Wl[kr][c4]) =
                    *reinterpret_cast<const float4*>(
                        W + (size_t)(k0 + kc * 32 + kr) * H_ + c4);
            }
            __syncthreads();

            #pragma unroll 4
            for (int k = 0; k < 32; ++k) {
                const float4 a0 = *reinterpret_cast<const float4*>(&At[k][rg * 8]);
                const float4 a1 = *reinterpret_cast<const float4*>(&At[k][rg * 8 + 4]);
                const float4 b0 = *reinterpret_cast<const float4*>(&Wl[k][cg * 4]);
                const float4 b1 = *reinterpret_cast<const float4*>(&Wl[k][64 + cg * 4]);
                const float aa[8] = {a0.x, a0.y, a0.z, a0.w, a1.x, a1.y, a1.z, a1.w};
                const float bb[8] = {b0.x, b0.y, b0.z, b0.w, b1.x, b1.y, b1.z, b1.w};
                #pragma unroll
                for (int r = 0; r < 8; ++r)
                    #pragma unroll
                    for (int c = 0; c < 8; ++c)
                        acc[r][c] = fmaf(aa[r], bb[c], acc[r][c]);
            }
        }

        float* __restrict__ dst = Pp + (size_t)blockIdx.y * (4096 * 128);
        #pragma unroll
        for (int r = 0; r < 8; ++r) {
            const int grow = xb * 128 + rg * 8 + r;
            *reinterpret_cast<float4*>(dst + (size_t)grow * H_ + cg * 4) =
                make_float4(acc[r][0], acc[r][1], acc[r][2], acc[r][3]);
            *reinterpret_cast<float4*>(dst + (size_t)grow * H_ + 64 + cg * 4) =
                make_float4(acc[r][4], acc[r][5], acc[r][6], acc[r][7]);
        }
    } else {
        const int id = (blockIdx.x - 32) * 8 + blockIdx.y;
        const int kt = id & 7, dt = (id >> 3) & 7, b = id >> 6;
        float (*Vl)[69] = (float(*)[69])smem;

        #pragma unroll
        for (int p = 0; p < 4; ++p) {
            const int idx = p * 256 + t;
            const int r  = idx >> 4;
            const int c4 = (idx & 15) * 4;
            const float4 v = *reinterpret_cast<const float4*>(
                V + ((size_t)b * NK_ + kt * 64 + r) * D_ + dt * 64 + c4);
            Vl[r][c4 + 0] = v.x; Vl[r][c4 + 1] = v.y;
            Vl[r][c4 + 2] = v.z; Vl[r][c4 + 3] = v.w;
        }
        __syncthreads();

        #pragma unroll
        for (int p = 0; p < 4; ++p) {
            const int idx = p * 256 + t;
            const int d  = idx >> 4;
            const int k4 = (idx & 15) * 4;
            ushort4 o;
            o.x = f2bf(Vl[k4 + 0][d]); o.y = f2bf(Vl[k4 + 1][d]);
            o.z = f2bf(Vl[k4 + 2][d]); o.w = f2bf(Vl[k4 + 3][d]);
            *reinterpret_cast<ushort4*>(
                Vt + ((size_t)b * D_ + dt * 64 + d) * NK_ + kt * 64 + k4) = o;
        }
    }
}

// ---------------------------------------------------------------------------
// proj_add: Eqk = exp2(C2 * sum_s Pp[s])  (C2 = 2*log2 e, so Eqk = e^{2*proj});
// builds wp pair table. grid 512, 256 thr.
// Score then uses e^{2(q+k)} = Eq*Ek — NO exp2 in the hot inner loop.
// ---------------------------------------------------------------------------
__global__ __launch_bounds__(256) void proj_add_kernel(
    const float* __restrict__ Pp, const float* __restrict__ wv,
    float* __restrict__ Eqk, float* __restrict__ wp)
{
    const int i = blockIdx.x * 256 + threadIdx.x;
    const float C2 = 2.88539008177792681472f;       // 2*log2(e)
    float4 s = make_float4(0.f, 0.f, 0.f, 0.f);
    #pragma unroll
    for (int p = 0; p < 8; ++p) {
        const float4 v = reinterpret_cast<const float4*>(Pp)[(size_t)p * 131072 + i];
        s.x += v.x; s.y += v.y; s.z += v.z; s.w += v.w;
    }
    s.x = fexp2(C2 * s.x); s.y = fexp2(C2 * s.y);
    s.z = fexp2(C2 * s.z); s.w = fexp2(C2 * s.w);
    reinterpret_cast<float4*>(Eqk)[i] = s;

    if (blockIdx.x == 0 && threadIdx.x < 64) {
        const float2 w2 = reinterpret_cast<const float2*>(wv)[threadIdx.x];
        const float wn0 = -2.0f * w2.x;
        const float wn1 = -2.0f * w2.y;
        reinterpret_cast<float4*>(wp)[threadIdx.x] =
            make_float4(wn0, wn1, wn0 + wn1, 0.0f);
    }
}

// ---------------------------------------------------------------------------
// score_softmax fused: block = 4 q-rows x full 512 k, 512 thr (8 waves).
// Wave w -> row rb*4 + (w>>1), k-half (w&1)*256 (4 chunks of 64, lane = k).
// score'[q,k] = sum_h wn_h / (1 + Eq_h*Ek_h), 4-way rcp fusion (1 rcp/4h,
// zero exp2). Cross-wave softmax combine via LDS (m,s per row-half; the
// s*exp2(m_w - M) rescale zeroes fully-masked halves exactly). Writes bf16.
// ---------------------------------------------------------------------------
__global__ __launch_bounds__(512, 4) void score_softmax_kernel(
    const float* __restrict__ Eqk, const float* __restrict__ wp,
    const int* __restrict__ valid_lens, unsigned short* __restrict__ Wbf)
{
    const int rb   = blockIdx.x;            // 0..511
    const int t    = threadIdx.x;
    const int w    = __builtin_amdgcn_readfirstlane(t >> 6);   // 0..7
    const int lane = t & 63;
    const int rloc = w >> 1;                // 0..3
    const int half = w & 1;                 // k-half
    const int row  = rb * 4 + rloc;         // 0..2047
    const int b    = row >> 9;

    __shared__ __align__(16) float4 Ks[2 * 64 * 33];   // two 64-k chunks
    __shared__ float redM[4][2], redS[4][2];

    const float4* __restrict__ Q4 =
        reinterpret_cast<const float4*>(Eqk + (size_t)row * H_);
    const float4* __restrict__ wp4 = reinterpret_cast<const float4*>(wp);
    const float4* __restrict__ Kp4 =
        reinterpret_cast<const float4*>(Eqk + (size_t)(2048 + b * NK_) * H_);

    float vals[4];

    for (int c = 0; c < 4; ++c) {
        if (c) __syncthreads();
        #pragma unroll
        for (int p = 0; p < 8; ++p) {
            const int idx = p * 512 + t;        // 0..4095
            const int hh  = idx >> 11;          // 0..1
            const int r   = (idx >> 5) & 63;    // 0..63
            const int h4  = idx & 31;
            Ks[(hh * 64 + r) * 33 + h4] =
                Kp4[(size_t)(hh * 256 + c * 64 + r) * 32 + h4];
        }
        __syncthreads();

        float s = 0.0f;
        #pragma unroll 4
        for (int g = 0; g < 32; ++g) {
            const float4 kv = Ks[(half * 64 + lane) * 33 + g];
            const float4 qa = Q4[g];
            const float4 wa = wp4[2 * g];
            const float4 wb = wp4[2 * g + 1];
            const float e0 = qa.x * kv.x;
            const float e1 = qa.y * kv.y;
            const float e2 = qa.z * kv.z;
            const float e3 = qa.w * kv.w;
            const float D01 = 1.0f + fmaf(e0, e1, e0 + e1);
            const float D23 = 1.0f + fmaf(e2, e3, e2 + e3);
            const float n01 = fmaf(wa.y, e0, fmaf(wa.x, e1, wa.z));
            const float n23 = fmaf(wb.y, e2, fmaf(wb.x, e3, wb.z));
            const float N   = fmaf(n23, D01, n01 * D23);
            s = fmaf(N, frcp(D01 * D23), s);
        }
        vals[c] = s;
    }

    // per-wave masked stats over this wave's 256 k
    const int vl = valid_lens[b];
    const float L2E = 1.44269504088896340736f;
    float m = -1e30f;
    #pragma unroll
    for (int c = 0; c < 4; ++c) {
        const int k = half * 256 + c * 64 + lane;
        vals[c] = (k < vl) ? vals[c] : -1e30f;
        m = fmaxf(m, vals[c]);
    }
    #pragma unroll
    for (int off = 32; off >= 1; off >>= 1)
        m = fmaxf(m, __shfl_xor(m, off, 64));
    float sum = 0.0f;
    #pragma unroll
    for (int c = 0; c < 4; ++c)
        sum += fexp2((vals[c] - m) * L2E);
    #pragma unroll
    for (int off = 32; off >= 1; off >>= 1)
        sum += __shfl_xor(sum, off, 64);

    if (lane == 0) { redM[rloc][half] = m; redS[rloc][half] = sum; }
    __syncthreads();

    const float m0 = redM[rloc][0], m1 = redM[rloc][1];
    const float s0 = redS[rloc][0], s1 = redS[rloc][1];
    const float M  = fmaxf(m0, m1);   // finite: vl>=1 so half 0 has a valid k
    const float S  = fmaf(s0, fexp2((m0 - M) * L2E),
                          s1 * fexp2((m1 - M) * L2E));
    const float inv = frcp(S);

    unsigned short* __restrict__ dst = Wbf + (size_t)row * NK_ + half * 256;
    #pragma unroll
    for (int c = 0; c < 4; ++c)
        dst[c * 64 + lane] = f2bf(fexp2((vals[c] - M) * L2E) * inv);
}

// ---------------------------------------------------------------------------
// av_gemm (bf16 MFMA 16x16x32): O[b] = W@V. Block 64q x 64d, 4 waves,
// grid (8,8,4). A (weights) and Bt (=V^T) k-contiguous -> ds_read_b128.
// ---------------------------------------------------------------------------
__global__ __launch_bounds__(256) void av_gemm_kernel(
    const unsigned short* __restrict__ Wbf, const unsigned short* __restrict__ Vt,
    float* __restrict__ O)
{
    const int c0 = blockIdx.x * 64;
    const int r0 = blockIdx.y * 64;
    const int b  = blockIdx.z;
    const int t  = threadIdx.x;
    const int wave = __builtin_amdgcn_readfirstlane(t >> 6);
    const int lane = t & 63;
    const int m    = lane & 15;
    const int quad = lane >> 4;

    __shared__ unsigned short Al [64][136];
    __shared__ unsigned short Btl[64][136];

    f32x4 acc0 = {0.f,0.f,0.f,0.f}, acc1 = {0.f,0.f,0.f,0.f};
    f32x4 acc2 = {0.f,0.f,0.f,0.f}, acc3 = {0.f,0.f,0.f,0.f};

    for (int kc = 0; kc < 4; ++kc) {
        if (kc) __syncthreads();
        #pragma unroll
        for (int p = 0; p < 4; ++p) {
            const int idx = p * 256 + t;
            const int rl = idx >> 4;
            const int k8 = (idx & 15) * 8;
            *reinterpret_cast<uint4*>(&Al[rl][k8]) =
                *reinterpret_cast<const uint4*>(
                    Wbf + ((size_t)b * NQ_ + r0 + rl) * NK_ + kc * 128 + k8);
            *reinterpret_cast<uint4*>(&Btl[rl][k8]) =
                *reinterpret_cast<const uint4*>(
                    Vt + ((size_t)b * D_ + c0 + rl) * NK_ + kc * 128 + k8);
        }
        __syncthreads();

        #pragma unroll
        for (int sub = 0; sub < 4; ++sub) {
            const int kcol = sub * 32 + quad * 8;
            const short8 a = *reinterpret_cast<const short8*>(&Al[wave * 16 + m][kcol]);
            const short8 b0 = *reinterpret_cast<const short8*>(&Btl[ 0 + m][kcol]);
            const short8 b1 = *reinterpret_cast<const short8*>(&Btl[16 + m][kcol]);
            const short8 b2 = *reinterpret_cast<const short8*>(&Btl[32 + m][kcol]);
            const short8 b3 = *reinterpret_cast<const short8*>(&Btl[48 + m][kcol]);
            acc0 = __builtin_amdgcn_mfma_f32_16x16x32_bf16(a, b0, acc0, 0, 0, 0);
            acc1 = __builtin_amdgcn_mfma_f32_16x16x32_bf16(a, b1, acc1, 0, 0, 0);
            acc2 = __builtin_amdgcn_mfma_f32_16x16x32_bf16(a, b2, acc2, 0, 0, 0);
            acc3 = __builtin_amdgcn_mfma_f32_16x16x32_bf16(a, b3, acc3, 0, 0, 0);
        }
    }

    const size_t rowbase = (size_t)b * NQ_ + r0 + wave * 16 + quad * 4;
    #pragma unroll
    for (int i = 0; i < 4; ++i) {
        float* __restrict__ orow = O + (rowbase + i) * D_ + c0 + m;
        orow[ 0] = acc0[i];
        orow[16] = acc1[i];
        orow[32] = acc2[i];
        orow[48] = acc3[i];
    }
}

extern "C" void kernel_launch(void* const* d_in, const int* in_sizes, int n_in,
                              void* d_out, int out_size, void* d_ws, size_t ws_size,
                              hipStream_t stream) {
    (void)in_sizes; (void)n_in; (void)out_size; (void)ws_size;

    const float* Q   = (const float*)d_in[0];
    const float* K   = (const float*)d_in[1];
    const float* V   = (const float*)d_in[2];
    const float* Wq  = (const float*)d_in[3];
    const float* Wk  = (const float*)d_in[4];
    const float* wv  = (const float*)d_in[5];
    const int*   vl  = (const int*)d_in[6];
    float* out = (float*)d_out;

    float* ws  = (float*)d_ws;
    float* Eqk = ws + WS_EQK;
    float* Pp  = ws + WS_PP;
    float* wp  = ws + WS_WP;
    unsigned short* Wbf = (unsigned short*)(ws + WS_WBF);
    unsigned short* Vt  = (unsigned short*)(ws + WS_VT);

    prep_kernel<<<dim3(64, 8), 256, 0, stream>>>(Q, K, Wq, Wk, V, Pp, Vt);
    proj_add_kernel<<<dim3(512), 256, 0, stream>>>(Pp, wv, Eqk, wp);
    score_softmax_kernel<<<dim3(512), 512, 0, stream>>>(Eqk, wp, vl, Wbf);
    av_gemm_kernel<<<dim3(8, 8, 4), 256, 0, stream>>>(Wbf, Vt, out);
}